// Round 1
// baseline (400.682 us; speedup 1.0000x reference)
//
#include <hip/hip_runtime.h>

typedef __attribute__((ext_vector_type(8))) __bf16 bf16x8;
typedef __attribute__((ext_vector_type(4))) float f32x4;

__device__ __forceinline__ unsigned short f2bf(float f) {
  union { float f; unsigned int u; } v; v.f = f;
  unsigned int r = v.u + 0x7FFFu + ((v.u >> 16) & 1u);
  return (unsigned short)(r >> 16);
}

__device__ __forceinline__ f32x4 mfma_bf16(bf16x8 a, bf16x8 b, f32x4 c) {
  return __builtin_amdgcn_mfma_f32_16x16x32_bf16(a, b, c, 0, 0, 0);
}

// ---------------- conversion kernels ----------------

__global__ void cvt_f32_bf16(const float* __restrict__ in, unsigned short* __restrict__ out, int n4) {
  int i = blockIdx.x * blockDim.x + threadIdx.x;
  if (i < n4) {
    float4 v = reinterpret_cast<const float4*>(in)[i];
    ushort4 o;
    o.x = f2bf(v.x); o.y = f2bf(v.y); o.z = f2bf(v.z); o.w = f2bf(v.w);
    reinterpret_cast<ushort4*>(out)[i] = o;
  }
}

// er[128][2048] f32  ->  ert[2048][128] bf16
__global__ void er_transpose(const float* __restrict__ er, unsigned short* __restrict__ ert) {
  int idx = blockIdx.x * blockDim.x + threadIdx.x;   // 262144 total
  int d = idx >> 11, w = idx & 2047;
  ert[w * 128 + d] = f2bf(er[idx]);
}

// ---------------- GEMM: C[MxN] = A[Mx1024] * Bt[Nx1024]^T + bias ----------------
// M = 4096, N = 1024, K = 1024 fixed. mode: 0 = bf16 row-major out,
// 1 = bf16 band-transposed Vt[(b*8+bd)*128+d][w] out, 2 = f32 row-major out.

__global__ __launch_bounds__(256, 2) void gemm_bt(
    const unsigned short* __restrict__ A,
    const unsigned short* __restrict__ Bt,
    const float* __restrict__ bias,
    void* __restrict__ C,
    int mode)
{
  __shared__ unsigned short lds[16896];        // Al: [0,4096) Bl: [4096,8192) ; reused for transpose
  unsigned short* Al = lds;
  unsigned short* Bl = lds + 4096;

  const int tid = threadIdx.x;
  const int lane = tid & 63, wid = tid >> 6;
  const int lr = lane & 15, lq = lane >> 4;
  const int wr = wid >> 1, wc = wid & 1;       // 2x2 waves, 64x64 each
  const int i0 = blockIdx.y * 128, j0 = blockIdx.x * 128;

  f32x4 acc[4][4] = {};

  const int srow = tid >> 2;                   // 0..63
  const int scolb = (tid & 3) << 4;            // 0,16,32,48 bytes

  for (int kt = 0; kt < 32; ++kt) {
    const int k0b = kt * 64;                   // byte offset along K
    __syncthreads();
    const char* As = (const char*)A + (size_t)(i0 + srow) * 2048 + k0b + scolb;
    const char* Bs = (const char*)Bt + (size_t)(j0 + srow) * 2048 + k0b + scolb;
    uint4 va0 = *(const uint4*)As;
    uint4 va1 = *(const uint4*)(As + 64 * 2048);
    uint4 vb0 = *(const uint4*)Bs;
    uint4 vb1 = *(const uint4*)(Bs + 64 * 2048);
    *(uint4*)((char*)Al + srow * 64 + scolb) = va0;
    *(uint4*)((char*)Al + (srow + 64) * 64 + scolb) = va1;
    *(uint4*)((char*)Bl + srow * 64 + scolb) = vb0;
    *(uint4*)((char*)Bl + (srow + 64) * 64 + scolb) = vb1;
    __syncthreads();

    bf16x8 af[4], bfr[4];
#pragma unroll
    for (int m = 0; m < 4; ++m)
      af[m] = *(const bf16x8*)((const char*)Al + (wr * 64 + m * 16 + lr) * 64 + lq * 16);
#pragma unroll
    for (int n = 0; n < 4; ++n)
      bfr[n] = *(const bf16x8*)((const char*)Bl + (wc * 64 + n * 16 + lr) * 64 + lq * 16);
#pragma unroll
    for (int m = 0; m < 4; ++m)
#pragma unroll
      for (int n = 0; n < 4; ++n)
        acc[m][n] = mfma_bf16(af[m], bfr[n], acc[m][n]);
  }

  float bv[4];
#pragma unroll
  for (int n = 0; n < 4; ++n) bv[n] = bias[j0 + wc * 64 + n * 16 + lr];

  if (mode == 1) {
    // transpose via LDS, write Vt[(b*8+bd)*128 + d][w] coalesced along w
    __syncthreads();
#pragma unroll
    for (int m = 0; m < 4; ++m)
#pragma unroll
      for (int n = 0; n < 4; ++n)
#pragma unroll
        for (int r = 0; r < 4; ++r) {
          int il = wr * 64 + m * 16 + lq * 4 + r;   // local row (w)
          int jl = wc * 64 + n * 16 + lr;           // local col (d)
          lds[jl * 132 + il] = f2bf(acc[m][n][r] + bv[n]);
        }
    __syncthreads();
    const int b = i0 >> 11, w0 = i0 & 2047, bd = j0 >> 7;
    unsigned short* out = (unsigned short*)C;
    for (int idx = tid; idx < 16384; idx += 256) {
      int dl = idx >> 7, wl = idx & 127;
      out[(size_t)((b * 8 + bd) * 128 + dl) * 2048 + w0 + wl] = lds[dl * 132 + wl];
    }
  } else if (mode == 0) {
    unsigned short* out = (unsigned short*)C;
#pragma unroll
    for (int m = 0; m < 4; ++m)
#pragma unroll
      for (int n = 0; n < 4; ++n)
#pragma unroll
        for (int r = 0; r < 4; ++r) {
          int gi = i0 + wr * 64 + m * 16 + lq * 4 + r;
          int gj = j0 + wc * 64 + n * 16 + lr;
          out[(size_t)gi * 1024 + gj] = f2bf(acc[m][n][r] + bv[n]);
        }
  } else {
    float* out = (float*)C;
#pragma unroll
    for (int m = 0; m < 4; ++m)
#pragma unroll
      for (int n = 0; n < 4; ++n)
#pragma unroll
        for (int r = 0; r < 4; ++r) {
          int gi = i0 + wr * 64 + m * 16 + lq * 4 + r;
          int gj = j0 + wc * 64 + n * 16 + lr;
          out[(size_t)gi * 1024 + gj] = acc[m][n][r] + bv[n];
        }
  }
}

// ---------------- fused attention ----------------
// grid (16 qtiles, 16 = b*8+band), 512 threads (8 waves x 16 q-rows).
// S[i,j] = (Q[qi+i]·K[kj+j] + ErT[qi+i]·Q[kj+j]) / 32 ; write to a_out;
// online softmax; O += P·V via Vt tiles; ctx out bf16.

__global__ __launch_bounds__(512) void attn_fused(
    const unsigned short* __restrict__ Qb,
    const unsigned short* __restrict__ Kb,
    const unsigned short* __restrict__ Vt,
    const unsigned short* __restrict__ ErT,
    float* __restrict__ a_out,
    unsigned short* __restrict__ ctx)
{
  __shared__ unsigned short Kl[16384];   // [krow][d] rows of 256B
  __shared__ unsigned short Ql[16384];   // Q[kj] tile, same layout
  __shared__ unsigned short Vl[16384];   // Vt tile [d][w]
  __shared__ unsigned short Pl[16384];   // P [qrow][krow]

  const int qt = blockIdx.x;
  const int bd = blockIdx.y & 7, b = blockIdx.y >> 3;
  const int qi0 = qt * 128;
  const int tid = threadIdx.x, wid = tid >> 6, lane = tid & 63;
  const int lr = lane & 15, lq = lane >> 4;

  // persistent A-fragments: Q[qi] rows and ErT[qi] rows (k = d = 128 -> 4 slices)
  bf16x8 qf[4], ef[4];
  {
    const unsigned short* Qrow = Qb + (size_t)(b * 2048 + qi0 + wid * 16 + lr) * 1024 + bd * 128;
    const unsigned short* Erow = ErT + (size_t)(qi0 + wid * 16 + lr) * 128;
#pragma unroll
    for (int kk = 0; kk < 4; ++kk) {
      qf[kk] = *(const bf16x8*)(Qrow + kk * 32 + lq * 8);
      ef[kk] = *(const bf16x8*)(Erow + kk * 32 + lq * 8);
    }
  }

  f32x4 oacc[8] = {};
  float M[4], L[4];
#pragma unroll
  for (int r = 0; r < 4; ++r) { M[r] = -1e30f; L[r] = 0.f; }

  float* abase = a_out + (size_t)(b * 8 + bd) * 2048 * 2048;

  for (int kt = 0; kt < 16; ++kt) {
    const int kj0 = kt * 128;
    __syncthreads();
    // stage K[kj], Q[kj], Vt tiles: 32KB each, 512 threads x 4 x 16B
#pragma unroll
    for (int p = 0; p < 4; ++p) {
      int linear = (p * 512 + tid) * 16;
      int row = linear >> 8, colb = linear & 255;
      const char* ks = (const char*)Kb + ((size_t)(b * 2048 + kj0 + row) * 1024 + bd * 128) * 2 + colb;
      const char* qs = (const char*)Qb + ((size_t)(b * 2048 + kj0 + row) * 1024 + bd * 128) * 2 + colb;
      const char* vs = (const char*)Vt + ((size_t)((b * 8 + bd) * 128 + row) * 2048 + kj0) * 2 + colb;
      *(uint4*)((char*)Kl + linear) = *(const uint4*)ks;
      *(uint4*)((char*)Ql + linear) = *(const uint4*)qs;
      *(uint4*)((char*)Vl + linear) = *(const uint4*)vs;
    }
    __syncthreads();

    // S = Q·K^T + ErT·Qk^T
    f32x4 sacc[8] = {};
#pragma unroll
    for (int kk = 0; kk < 4; ++kk) {
#pragma unroll
      for (int nf = 0; nf < 8; ++nf) {
        bf16x8 kf = *(const bf16x8*)((const char*)Kl + (nf * 16 + lr) * 256 + kk * 64 + lq * 16);
        sacc[nf] = mfma_bf16(qf[kk], kf, sacc[nf]);
      }
#pragma unroll
      for (int nf = 0; nf < 8; ++nf) {
        bf16x8 qkf = *(const bf16x8*)((const char*)Ql + (nf * 16 + lr) * 256 + kk * 64 + lq * 16);
        sacc[nf] = mfma_bf16(ef[kk], qkf, sacc[nf]);
      }
    }

    // scale by 1/sqrt(1024) and emit `a`
#pragma unroll
    for (int nf = 0; nf < 8; ++nf)
#pragma unroll
      for (int r = 0; r < 4; ++r) sacc[nf][r] *= 0.03125f;
    {
      const int qrow_base = qi0 + wid * 16 + lq * 4;
#pragma unroll
      for (int nf = 0; nf < 8; ++nf)
#pragma unroll
        for (int r = 0; r < 4; ++r)
          abase[(size_t)(qrow_base + r) * 2048 + kj0 + nf * 16 + lr] = sacc[nf][r];
    }

    // online softmax (rows live on 16-lane groups sharing lq)
    float rmax[4];
#pragma unroll
    for (int r = 0; r < 4; ++r) {
      float m0 = sacc[0][r];
#pragma unroll
      for (int nf = 1; nf < 8; ++nf) m0 = fmaxf(m0, sacc[nf][r]);
      rmax[r] = m0;
    }
#pragma unroll
    for (int r = 0; r < 4; ++r) {
      rmax[r] = fmaxf(rmax[r], __shfl_xor(rmax[r], 1));
      rmax[r] = fmaxf(rmax[r], __shfl_xor(rmax[r], 2));
      rmax[r] = fmaxf(rmax[r], __shfl_xor(rmax[r], 4));
      rmax[r] = fmaxf(rmax[r], __shfl_xor(rmax[r], 8));
    }
    float scale[4], rsum[4];
#pragma unroll
    for (int r = 0; r < 4; ++r) {
      float Mn = fmaxf(M[r], rmax[r]);
      scale[r] = __expf(M[r] - Mn);
      M[r] = Mn;
      rsum[r] = 0.f;
    }
#pragma unroll
    for (int nf = 0; nf < 8; ++nf)
#pragma unroll
      for (int r = 0; r < 4; ++r) {
        float pv = __expf(sacc[nf][r] - M[r]);
        sacc[nf][r] = pv;
        rsum[r] += pv;
      }
    // P -> LDS (bf16), wave-local rows
    {
      const int prow = wid * 16 + lq * 4;
#pragma unroll
      for (int nf = 0; nf < 8; ++nf)
#pragma unroll
        for (int r = 0; r < 4; ++r)
          Pl[(prow + r) * 128 + nf * 16 + lr] = f2bf(sacc[nf][r]);
    }
#pragma unroll
    for (int r = 0; r < 4; ++r) {
      rsum[r] += __shfl_xor(rsum[r], 1);
      rsum[r] += __shfl_xor(rsum[r], 2);
      rsum[r] += __shfl_xor(rsum[r], 4);
      rsum[r] += __shfl_xor(rsum[r], 8);
      L[r] = L[r] * scale[r] + rsum[r];
    }
#pragma unroll
    for (int dn = 0; dn < 8; ++dn)
#pragma unroll
      for (int r = 0; r < 4; ++r) oacc[dn][r] *= scale[r];

    // O += P · V   (A = P rows from Pl, B = Vt rows from Vl)
#pragma unroll
    for (int kk = 0; kk < 4; ++kk) {
      bf16x8 pf = *(const bf16x8*)((const char*)Pl + (wid * 16 + lr) * 256 + kk * 64 + lq * 16);
#pragma unroll
      for (int dn = 0; dn < 8; ++dn) {
        bf16x8 vf = *(const bf16x8*)((const char*)Vl + (dn * 16 + lr) * 256 + kk * 64 + lq * 16);
        oacc[dn] = mfma_bf16(pf, vf, oacc[dn]);
      }
    }
  }

  // epilogue: ctx = O / L  -> bf16 [b*2048+w][bd*128+d]
  {
    const int qrow_base = b * 2048 + qi0 + wid * 16 + lq * 4;
#pragma unroll
    for (int dn = 0; dn < 8; ++dn)
#pragma unroll
      for (int r = 0; r < 4; ++r) {
        float v = oacc[dn][r] / L[r];
        ctx[(size_t)(qrow_base + r) * 1024 + bd * 128 + dn * 16 + lr] = f2bf(v);
      }
  }
}

// ---------------- launch ----------------

extern "C" void kernel_launch(void* const* d_in, const int* in_sizes, int n_in,
                              void* d_out, int out_size, void* d_ws, size_t ws_size,
                              hipStream_t stream) {
  const float* x  = (const float*)d_in[0];
  const float* Wq = (const float*)d_in[1];
  const float* bq = (const float*)d_in[2];
  const float* Wk = (const float*)d_in[3];
  const float* bk = (const float*)d_in[4];
  const float* Wv = (const float*)d_in[5];
  const float* bv = (const float*)d_in[6];
  const float* Wo = (const float*)d_in[7];
  const float* bo = (const float*)d_in[8];
  const float* er = (const float*)d_in[9];

  char* ws = (char*)d_ws;
  unsigned short* xb  = (unsigned short*)(ws + 0);          //  8 MB  x bf16
  unsigned short* Wqb = (unsigned short*)(ws + 8388608);    //  2 MB
  unsigned short* Wkb = (unsigned short*)(ws + 10485760);   //  2 MB
  unsigned short* Wvb = (unsigned short*)(ws + 12582912);   //  2 MB
  unsigned short* Wob = (unsigned short*)(ws + 14680064);   //  2 MB
  unsigned short* Qb  = (unsigned short*)(ws + 16777216);   //  8 MB
  unsigned short* Kb  = (unsigned short*)(ws + 25165824);   //  8 MB
  unsigned short* Vtb = (unsigned short*)(ws + 33554432);   //  8 MB  [16][128][2048]
  unsigned short* ctx = (unsigned short*)(ws + 41943040);   //  8 MB
  unsigned short* ert = (unsigned short*)(ws + 50331648);   //  0.5 MB [2048][128]

  float* o_out = (float*)d_out;                   // 4,194,304 floats
  float* a_out = (float*)d_out + 4194304;         // 67,108,864 floats

  cvt_f32_bf16<<<dim3(4096), dim3(256), 0, stream>>>(x, xb, 1048576);
  cvt_f32_bf16<<<dim3(1024), dim3(256), 0, stream>>>(Wq, Wqb, 262144);
  cvt_f32_bf16<<<dim3(1024), dim3(256), 0, stream>>>(Wk, Wkb, 262144);
  cvt_f32_bf16<<<dim3(1024), dim3(256), 0, stream>>>(Wv, Wvb, 262144);
  cvt_f32_bf16<<<dim3(1024), dim3(256), 0, stream>>>(Wo, Wob, 262144);
  er_transpose<<<dim3(1024), dim3(256), 0, stream>>>(er, ert);

  gemm_bt<<<dim3(8, 32), dim3(256), 0, stream>>>(xb, Wqb, bq, (void*)Qb, 0);
  gemm_bt<<<dim3(8, 32), dim3(256), 0, stream>>>(xb, Wkb, bk, (void*)Kb, 0);
  gemm_bt<<<dim3(8, 32), dim3(256), 0, stream>>>(xb, Wvb, bv, (void*)Vtb, 1);

  attn_fused<<<dim3(16, 16), dim3(512), 0, stream>>>(Qb, Kb, Vtb, ert, a_out, ctx);

  gemm_bt<<<dim3(8, 32), dim3(256), 0, stream>>>(ctx, Wob, bo, d_out, 2);
}

// Round 2
// 282.146 us; speedup vs baseline: 1.4201x; 1.4201x over previous
//
#include <hip/hip_runtime.h>

typedef __attribute__((ext_vector_type(8))) __bf16 bf16x8;
typedef __attribute__((ext_vector_type(4))) float f32x4;

__device__ __forceinline__ unsigned short f2bf(float f) {
  union { float f; unsigned int u; } v; v.f = f;
  unsigned int r = v.u + 0x7FFFu + ((v.u >> 16) & 1u);
  return (unsigned short)(r >> 16);
}

__device__ __forceinline__ f32x4 mfma_bf16(bf16x8 a, bf16x8 b, f32x4 c) {
  return __builtin_amdgcn_mfma_f32_16x16x32_bf16(a, b, c, 0, 0, 0);
}

__device__ __forceinline__ void gload_lds16(const void* g, void* l) {
  __builtin_amdgcn_global_load_lds((const __attribute__((address_space(1))) void*)g,
                                   (__attribute__((address_space(3))) void*)l, 16, 0, 0);
}

// ---------------- conversion kernels ----------------

__global__ void cvt_f32_bf16(const float* __restrict__ in, unsigned short* __restrict__ out, int n4) {
  int i = blockIdx.x * blockDim.x + threadIdx.x;
  if (i < n4) {
    float4 v = reinterpret_cast<const float4*>(in)[i];
    ushort4 o;
    o.x = f2bf(v.x); o.y = f2bf(v.y); o.z = f2bf(v.z); o.w = f2bf(v.w);
    reinterpret_cast<ushort4*>(out)[i] = o;
  }
}

// er[128][2048] f32  ->  ert[2048][128] bf16
__global__ void er_transpose(const float* __restrict__ er, unsigned short* __restrict__ ert) {
  int idx = blockIdx.x * blockDim.x + threadIdx.x;   // 262144 total
  int d = idx >> 11, w = idx & 2047;
  ert[w * 128 + d] = f2bf(er[idx]);
}

// ---------------- GEMM: C[MxN] = A[Mx1024] * Bt[Nx1024]^T + bias ----------------
// grid (32 Mtiles, 8 Ntiles) so XCD = Mtile%8 (L2 groups A-panels).
// mode: 0 = bf16 row-major out, 1 = bf16 band-transposed Vt out, 2 = f32 out.

__global__ __launch_bounds__(256, 2) void gemm_bt(
    const unsigned short* __restrict__ A,
    const unsigned short* __restrict__ Bt,
    const float* __restrict__ bias,
    void* __restrict__ C,
    int mode)
{
  __shared__ unsigned short lds[16896];        // Al: bytes [0,8192) Bl: [8192,16384)
  unsigned short* Al = lds;
  unsigned short* Bl = lds + 4096;

  const int tid = threadIdx.x;
  const int lane = tid & 63, wid = tid >> 6;
  const int lr = lane & 15, lq = lane >> 4;
  const int wr = wid >> 1, wc = wid & 1;       // 2x2 waves, 64x64 each
  const int i0 = blockIdx.x * 128, j0 = blockIdx.y * 128;

  f32x4 acc[4][4] = {};

  const int srow = tid >> 2;                   // 0..63
  const int scolb = (tid & 3) << 4;            // 0,16,32,48 bytes

  const char* Abase = (const char*)A + (size_t)(i0 + srow) * 2048 + scolb;
  const char* Bbase = (const char*)Bt + (size_t)(j0 + srow) * 2048 + scolb;

  for (int kt = 0; kt < 32; ++kt) {
    const int k0b = kt * 64;                   // byte offset along K
    __syncthreads();
    gload_lds16(Abase + k0b,             (char*)Al + tid * 16);
    gload_lds16(Abase + k0b + 64 * 2048, (char*)Al + 4096 + tid * 16);
    gload_lds16(Bbase + k0b,             (char*)Bl + tid * 16);
    gload_lds16(Bbase + k0b + 64 * 2048, (char*)Bl + 4096 + tid * 16);
    __syncthreads();

    bf16x8 af[4], bfr[4];
#pragma unroll
    for (int m = 0; m < 4; ++m)
      af[m] = *(const bf16x8*)((const char*)Al + (wr * 64 + m * 16 + lr) * 64 + lq * 16);
#pragma unroll
    for (int n = 0; n < 4; ++n)
      bfr[n] = *(const bf16x8*)((const char*)Bl + (wc * 64 + n * 16 + lr) * 64 + lq * 16);
    __builtin_amdgcn_s_setprio(1);
#pragma unroll
    for (int m = 0; m < 4; ++m)
#pragma unroll
      for (int n = 0; n < 4; ++n)
        acc[m][n] = mfma_bf16(af[m], bfr[n], acc[m][n]);
    __builtin_amdgcn_s_setprio(0);
  }

  float bv[4];
#pragma unroll
  for (int n = 0; n < 4; ++n) bv[n] = bias[j0 + wc * 64 + n * 16 + lr];

  if (mode == 1) {
    // transpose via LDS, write Vt[(b*8+bd)*128 + d][w] coalesced along w
    __syncthreads();
#pragma unroll
    for (int m = 0; m < 4; ++m)
#pragma unroll
      for (int n = 0; n < 4; ++n)
#pragma unroll
        for (int r = 0; r < 4; ++r) {
          int il = wr * 64 + m * 16 + lq * 4 + r;   // local row (w)
          int jl = wc * 64 + n * 16 + lr;           // local col (d)
          lds[jl * 132 + il] = f2bf(acc[m][n][r] + bv[n]);
        }
    __syncthreads();
    const int b = i0 >> 11, w0 = i0 & 2047, bd = j0 >> 7;
    unsigned short* out = (unsigned short*)C;
    for (int idx = tid; idx < 16384; idx += 256) {
      int dl = idx >> 7, wl = idx & 127;
      out[(size_t)((b * 8 + bd) * 128 + dl) * 2048 + w0 + wl] = lds[dl * 132 + wl];
    }
  } else if (mode == 0) {
    unsigned short* out = (unsigned short*)C;
#pragma unroll
    for (int m = 0; m < 4; ++m)
#pragma unroll
      for (int n = 0; n < 4; ++n)
#pragma unroll
        for (int r = 0; r < 4; ++r) {
          int gi = i0 + wr * 64 + m * 16 + lq * 4 + r;
          int gj = j0 + wc * 64 + n * 16 + lr;
          out[(size_t)gi * 1024 + gj] = f2bf(acc[m][n][r] + bv[n]);
        }
  } else {
    float* out = (float*)C;
#pragma unroll
    for (int m = 0; m < 4; ++m)
#pragma unroll
      for (int n = 0; n < 4; ++n)
#pragma unroll
        for (int r = 0; r < 4; ++r) {
          int gi = i0 + wr * 64 + m * 16 + lq * 4 + r;
          int gj = j0 + wc * 64 + n * 16 + lr;
          out[(size_t)gi * 1024 + gj] = acc[m][n][r] + bv[n];
        }
  }
}

// ---------------- fused attention ----------------
// grid (16 = b*8+band, 16 qtiles): linear%8 = band%8 -> all q-tiles of a band
// share an XCD's L2. 512 threads (8 waves x 16 q-rows).
// All LDS tiles XOR-swizzled: byte ^= (row&7)<<4 within each 256B row.

__global__ __launch_bounds__(512) void attn_fused(
    const unsigned short* __restrict__ Qb,
    const unsigned short* __restrict__ Kb,
    const unsigned short* __restrict__ Vt,
    const unsigned short* __restrict__ ErT,
    float* __restrict__ a_out,
    unsigned short* __restrict__ ctx)
{
  __shared__ unsigned short Kl[16384];   // [krow][d] rows of 256B, swizzled
  __shared__ unsigned short Ql[16384];   // Q[kj] tile, same layout
  __shared__ unsigned short Vl[16384];   // Vt tile [d][w], swizzled
  __shared__ unsigned short Pl[16384];   // P [qrow][krow], swizzled

  const int bd = blockIdx.x & 7, b = blockIdx.x >> 3;
  const int qt = blockIdx.y;
  const int qi0 = qt * 128;
  const int tid = threadIdx.x, wid = tid >> 6, lane = tid & 63;
  const int lr = lane & 15, lq = lane >> 4;

  char* Klb = (char*)Kl;
  char* Qlb = (char*)Ql;
  char* Vlb = (char*)Vl;
  char* Plb = (char*)Pl;

  // persistent A-fragments: Q[qi] rows and ErT[qi] rows (k = d = 128 -> 4 slices)
  bf16x8 qf[4], ef[4];
  {
    const unsigned short* Qrow = Qb + (size_t)(b * 2048 + qi0 + wid * 16 + lr) * 1024 + bd * 128;
    const unsigned short* Erow = ErT + (size_t)(qi0 + wid * 16 + lr) * 128;
#pragma unroll
    for (int kk = 0; kk < 4; ++kk) {
      qf[kk] = *(const bf16x8*)(Qrow + kk * 32 + lq * 8);
      ef[kk] = *(const bf16x8*)(Erow + kk * 32 + lq * 8);
    }
  }

  // staging geometry (constant across kt): 3 tiles x 32KB, 512 thr x 4 x 16B
  int dsto[4];
  const char* ksrc[4];
  const char* qsrc[4];
  const char* vsrc[4];
#pragma unroll
  for (int p = 0; p < 4; ++p) {
    int linear = (p * 512 + tid) * 16;
    int row = linear >> 8, colb = linear & 255;
    dsto[p] = row * 256 + (colb ^ ((row & 7) << 4));
    ksrc[p] = (const char*)Kb + ((size_t)(b * 2048 + row) * 1024 + bd * 128) * 2 + colb;
    qsrc[p] = (const char*)Qb + ((size_t)(b * 2048 + row) * 1024 + bd * 128) * 2 + colb;
    vsrc[p] = (const char*)Vt + ((size_t)((b * 8 + bd) * 128 + row) * 2048) * 2 + colb;
  }

  // prefetch tile 0
  uint4 rk[4], rq[4], rv[4];
#pragma unroll
  for (int p = 0; p < 4; ++p) {
    rk[p] = *(const uint4*)(ksrc[p]);
    rq[p] = *(const uint4*)(qsrc[p]);
    rv[p] = *(const uint4*)(vsrc[p]);
  }

  f32x4 oacc[8] = {};
  float M[4], L[4];
#pragma unroll
  for (int r = 0; r < 4; ++r) { M[r] = -1e30f; L[r] = 0.f; }

  float* abase = a_out + (size_t)(b * 8 + bd) * 2048 * 2048;

  for (int kt = 0; kt < 16; ++kt) {
    const int kj0 = kt * 128;
    __syncthreads();                       // previous compute done reading LDS
#pragma unroll
    for (int p = 0; p < 4; ++p) {
      *(uint4*)(Klb + dsto[p]) = rk[p];
      *(uint4*)(Qlb + dsto[p]) = rq[p];
      *(uint4*)(Vlb + dsto[p]) = rv[p];
    }
    if (kt < 15) {                         // async prefetch of next tile
      const size_t kqoff = (size_t)(kt + 1) * 262144;   // +128 rows
      const size_t voff = (size_t)(kt + 1) * 256;       // +128 cols
#pragma unroll
      for (int p = 0; p < 4; ++p) {
        rk[p] = *(const uint4*)(ksrc[p] + kqoff);
        rq[p] = *(const uint4*)(qsrc[p] + kqoff);
        rv[p] = *(const uint4*)(vsrc[p] + voff);
      }
    }
    __syncthreads();                       // LDS tiles ready

    // S = Q·K^T + ErT·Qk^T
    f32x4 sacc[8] = {};
    __builtin_amdgcn_s_setprio(1);
#pragma unroll
    for (int kk = 0; kk < 4; ++kk) {
#pragma unroll
      for (int nf = 0; nf < 8; ++nf) {
        const int row = nf * 16 + lr;
        bf16x8 kf = *(const bf16x8*)(Klb + row * 256 + ((kk * 64 + lq * 16) ^ ((row & 7) << 4)));
        sacc[nf] = mfma_bf16(qf[kk], kf, sacc[nf]);
      }
#pragma unroll
      for (int nf = 0; nf < 8; ++nf) {
        const int row = nf * 16 + lr;
        bf16x8 qkf = *(const bf16x8*)(Qlb + row * 256 + ((kk * 64 + lq * 16) ^ ((row & 7) << 4)));
        sacc[nf] = mfma_bf16(ef[kk], qkf, sacc[nf]);
      }
    }
    __builtin_amdgcn_s_setprio(0);

    // scale by 1/sqrt(1024) and emit `a` (streamed, nontemporal)
#pragma unroll
    for (int nf = 0; nf < 8; ++nf)
#pragma unroll
      for (int r = 0; r < 4; ++r) sacc[nf][r] *= 0.03125f;
    {
      const int qrow_base = qi0 + wid * 16 + lq * 4;
#pragma unroll
      for (int nf = 0; nf < 8; ++nf)
#pragma unroll
        for (int r = 0; r < 4; ++r)
          __builtin_nontemporal_store(sacc[nf][r],
              abase + (size_t)(qrow_base + r) * 2048 + kj0 + nf * 16 + lr);
    }

    // online softmax (rows live on 16-lane groups sharing lq)
    float rmax[4];
#pragma unroll
    for (int r = 0; r < 4; ++r) {
      float m0 = sacc[0][r];
#pragma unroll
      for (int nf = 1; nf < 8; ++nf) m0 = fmaxf(m0, sacc[nf][r]);
      rmax[r] = m0;
    }
#pragma unroll
    for (int r = 0; r < 4; ++r) {
      rmax[r] = fmaxf(rmax[r], __shfl_xor(rmax[r], 1));
      rmax[r] = fmaxf(rmax[r], __shfl_xor(rmax[r], 2));
      rmax[r] = fmaxf(rmax[r], __shfl_xor(rmax[r], 4));
      rmax[r] = fmaxf(rmax[r], __shfl_xor(rmax[r], 8));
    }
    float scale[4], rsum[4];
#pragma unroll
    for (int r = 0; r < 4; ++r) {
      float Mn = fmaxf(M[r], rmax[r]);
      scale[r] = __expf(M[r] - Mn);
      M[r] = Mn;
      rsum[r] = 0.f;
    }
#pragma unroll
    for (int nf = 0; nf < 8; ++nf)
#pragma unroll
      for (int r = 0; r < 4; ++r) {
        float pv = __expf(sacc[nf][r] - M[r]);
        sacc[nf][r] = pv;
        rsum[r] += pv;
      }
    // P -> LDS (bf16), wave-local rows, swizzled
    {
      const int prow0 = wid * 16 + lq * 4;
#pragma unroll
      for (int nf = 0; nf < 8; ++nf)
#pragma unroll
        for (int r = 0; r < 4; ++r) {
          const int row = prow0 + r;
          *(unsigned short*)(Plb + row * 256 + (((nf * 16 + lr) * 2) ^ ((row & 7) << 4))) =
              f2bf(sacc[nf][r]);
        }
    }
#pragma unroll
    for (int r = 0; r < 4; ++r) {
      rsum[r] += __shfl_xor(rsum[r], 1);
      rsum[r] += __shfl_xor(rsum[r], 2);
      rsum[r] += __shfl_xor(rsum[r], 4);
      rsum[r] += __shfl_xor(rsum[r], 8);
      L[r] = L[r] * scale[r] + rsum[r];
    }
#pragma unroll
    for (int dn = 0; dn < 8; ++dn)
#pragma unroll
      for (int r = 0; r < 4; ++r) oacc[dn][r] *= scale[r];

    // O += P · V   (A = P rows from Pl, B = Vt rows from Vl)
    __builtin_amdgcn_s_setprio(1);
#pragma unroll
    for (int kk = 0; kk < 4; ++kk) {
      const int prow = wid * 16 + lr;
      bf16x8 pf = *(const bf16x8*)(Plb + prow * 256 + ((kk * 64 + lq * 16) ^ ((prow & 7) << 4)));
#pragma unroll
      for (int dn = 0; dn < 8; ++dn) {
        const int vrow = dn * 16 + lr;
        bf16x8 vf = *(const bf16x8*)(Vlb + vrow * 256 + ((kk * 64 + lq * 16) ^ ((vrow & 7) << 4)));
        oacc[dn] = mfma_bf16(pf, vf, oacc[dn]);
      }
    }
    __builtin_amdgcn_s_setprio(0);
  }

  // epilogue: ctx = O / L  -> bf16 [b*2048+w][bd*128+d]
  {
    const int qrow_base = b * 2048 + qi0 + wid * 16 + lq * 4;
#pragma unroll
    for (int dn = 0; dn < 8; ++dn)
#pragma unroll
      for (int r = 0; r < 4; ++r) {
        float v = oacc[dn][r] / L[r];
        ctx[(size_t)(qrow_base + r) * 1024 + bd * 128 + dn * 16 + lr] = f2bf(v);
      }
  }
}

// ---------------- launch ----------------

extern "C" void kernel_launch(void* const* d_in, const int* in_sizes, int n_in,
                              void* d_out, int out_size, void* d_ws, size_t ws_size,
                              hipStream_t stream) {
  const float* x  = (const float*)d_in[0];
  const float* Wq = (const float*)d_in[1];
  const float* bq = (const float*)d_in[2];
  const float* Wk = (const float*)d_in[3];
  const float* bk = (const float*)d_in[4];
  const float* Wv = (const float*)d_in[5];
  const float* bv = (const float*)d_in[6];
  const float* Wo = (const float*)d_in[7];
  const float* bo = (const float*)d_in[8];
  const float* er = (const float*)d_in[9];

  char* ws = (char*)d_ws;
  unsigned short* xb  = (unsigned short*)(ws + 0);          //  8 MB  x bf16
  unsigned short* Wqb = (unsigned short*)(ws + 8388608);    //  2 MB
  unsigned short* Wkb = (unsigned short*)(ws + 10485760);   //  2 MB
  unsigned short* Wvb = (unsigned short*)(ws + 12582912);   //  2 MB
  unsigned short* Wob = (unsigned short*)(ws + 14680064);   //  2 MB
  unsigned short* Qb  = (unsigned short*)(ws + 16777216);   //  8 MB
  unsigned short* Kb  = (unsigned short*)(ws + 25165824);   //  8 MB
  unsigned short* Vtb = (unsigned short*)(ws + 33554432);   //  8 MB  [16][128][2048]
  unsigned short* ctx = (unsigned short*)(ws + 41943040);   //  8 MB
  unsigned short* ert = (unsigned short*)(ws + 50331648);   //  0.5 MB [2048][128]

  float* a_out = (float*)d_out + 4194304;         // 67,108,864 floats

  cvt_f32_bf16<<<dim3(4096), dim3(256), 0, stream>>>(x, xb, 1048576);
  cvt_f32_bf16<<<dim3(1024), dim3(256), 0, stream>>>(Wq, Wqb, 262144);
  cvt_f32_bf16<<<dim3(1024), dim3(256), 0, stream>>>(Wk, Wkb, 262144);
  cvt_f32_bf16<<<dim3(1024), dim3(256), 0, stream>>>(Wv, Wvb, 262144);
  cvt_f32_bf16<<<dim3(1024), dim3(256), 0, stream>>>(Wo, Wob, 262144);
  er_transpose<<<dim3(1024), dim3(256), 0, stream>>>(er, ert);

  gemm_bt<<<dim3(32, 8), dim3(256), 0, stream>>>(xb, Wqb, bq, (void*)Qb, 0);
  gemm_bt<<<dim3(32, 8), dim3(256), 0, stream>>>(xb, Wkb, bk, (void*)Kb, 0);
  gemm_bt<<<dim3(32, 8), dim3(256), 0, stream>>>(xb, Wvb, bv, (void*)Vtb, 1);

  attn_fused<<<dim3(16, 16), dim3(512), 0, stream>>>(Qb, Kb, Vtb, ert, a_out, ctx);

  gemm_bt<<<dim3(32, 8), dim3(256), 0, stream>>>(ctx, Wob, bo, d_out, 2);
}